// Round 1
// baseline (125.605 us; speedup 1.0000x reference)
//
#include <hip/hip_runtime.h>
#include <hip/hip_bf16.h>

#define B_   128
#define N_   65536
#define F_   512
#define CS   64
#define CPR  (N_ / CS)   // 1024 chunks per row
#define KPOS ((float)(511.0 / 65535.0))

// ws layout (floats):
//   coef  [B_][F_][5]        : 327680 floats
//   trans [B_][CPR][6]       : 786432 floats  (A00,A01,A10,A11,v0,v1)
//   states[B_][CPR][2]       : 262144 floats  (y[n0-1], y[n0-2])
#define OFF_COEF   0
#define OFF_TRANS  (B_ * F_ * 5)
#define OFF_STATES (OFF_TRANS + B_ * CPR * 6)

__global__ void coeff_kernel(const float* __restrict__ logits, float* __restrict__ coef) {
    int t = blockIdx.x * blockDim.x + threadIdx.x;
    if (t >= B_ * F_) return;
    const float* L = logits + (size_t)t * 5;
    float l0 = L[0], l1 = L[1], l2 = L[2], l3 = L[3], l4 = L[4];
    float a1 = 2.0f * tanhf(l0);
    float ab = fabsf(a1);
    float a2 = 0.5f * ((2.0f - ab) * tanhf(l1) + ab);
    float* C = coef + (size_t)t * 5;
    C[0] = a1; C[1] = a2; C[2] = l2; C[3] = l3; C[4] = l4;
}

// Each thread: compose the 64 per-sample affine transforms of its chunk.
__global__ void phase1_kernel(const float* __restrict__ x, const float* __restrict__ coef,
                              float* __restrict__ trans) {
    int t = blockIdx.x * blockDim.x + threadIdx.x;   // t < B_*CPR
    int b = t >> 10;
    int c = t & (CPR - 1);
    int n0 = c * CS;

    int I = min((int)floorf((float)n0 * KPOS), F_ - 2);
    int I2 = min(I + 2, F_ - 1);
    const float* Cb = coef + (size_t)b * F_ * 5;
    float a1A = Cb[I * 5 + 0],  a2A = Cb[I * 5 + 1];
    float a1B = Cb[(I + 1) * 5 + 0], a2B = Cb[(I + 1) * 5 + 1];
    float a1C = Cb[I2 * 5 + 0], a2C = Cb[I2 * 5 + 1];

    const float* xp = x + (size_t)b * N_ + n0;
    float A00 = 1.f, A01 = 0.f, A10 = 0.f, A11 = 1.f, v0 = 0.f, v1 = 0.f;
    #pragma unroll 8
    for (int k = 0; k < CS; ++k) {
        float xn = xp[k];
        float pos = (float)(n0 + k) * KPOS;
        int i0 = min((int)floorf(pos), F_ - 2);
        float frac = pos - (float)i0;
        float om = 1.0f - frac;
        bool sel = i0 > I;
        float lo1 = sel ? a1B : a1A, hi1 = sel ? a1C : a1B;
        float lo2 = sel ? a2B : a2A, hi2 = sel ? a2C : a2B;
        float a1 = om * lo1 + frac * hi1;
        float a2 = om * lo2 + frac * hi2;
        float nA00 = -a1 * A00 - a2 * A10;
        float nA01 = -a1 * A01 - a2 * A11;
        float nv0  = xn - a1 * v0 - a2 * v1;
        A10 = A00; A11 = A01; v1 = v0;
        A00 = nA00; A01 = nA01; v0 = nv0;
    }
    float* T = trans + (size_t)t * 6;
    T[0] = A00; T[1] = A01; T[2] = A10; T[3] = A11; T[4] = v0; T[5] = v1;
}

// One block per row: Hillis-Steele inclusive scan over 1024 chunk transforms.
// Emits each chunk's start state (the v-part of the exclusive prefix).
__global__ __launch_bounds__(1024) void scan_kernel(const float* __restrict__ trans,
                                                    float* __restrict__ states) {
    __shared__ float sh[CPR][6];
    int b = blockIdx.x;
    int c = threadIdx.x;
    const float* T = trans + ((size_t)b * CPR + c) * 6;
    float A00 = T[0], A01 = T[1], A10 = T[2], A11 = T[3], v0 = T[4], v1 = T[5];
    for (int d = 1; d < CPR; d <<= 1) {
        sh[c][0] = A00; sh[c][1] = A01; sh[c][2] = A10; sh[c][3] = A11;
        sh[c][4] = v0;  sh[c][5] = v1;
        __syncthreads();
        if (c >= d) {
            float f00 = sh[c - d][0], f01 = sh[c - d][1];
            float f10 = sh[c - d][2], f11 = sh[c - d][3];
            float fv0 = sh[c - d][4], fv1 = sh[c - d][5];
            // new = mine (later) ∘ f (earlier)
            float n00 = A00 * f00 + A01 * f10;
            float n01 = A00 * f01 + A01 * f11;
            float n10 = A10 * f00 + A11 * f10;
            float n11 = A10 * f01 + A11 * f11;
            float nv0 = A00 * fv0 + A01 * fv1 + v0;
            float nv1 = A10 * fv0 + A11 * fv1 + v1;
            A00 = n00; A01 = n01; A10 = n10; A11 = n11; v0 = nv0; v1 = nv1;
        }
        __syncthreads();
    }
    float* S = states + (size_t)b * CPR * 2;
    if (c == 0) { S[0] = 0.f; S[1] = 0.f; }
    if (c < CPR - 1) { S[(c + 1) * 2] = v0; S[(c + 1) * 2 + 1] = v1; }
}

// Each thread: re-run the recurrence over its chunk from the exact start state,
// fuse the time-varying FIR, write output.
__global__ void phase3_kernel(const float* __restrict__ x, const float* __restrict__ coef,
                              const float* __restrict__ states, float* __restrict__ out) {
    int t = blockIdx.x * blockDim.x + threadIdx.x;   // t < B_*CPR
    int b = t >> 10;
    int c = t & (CPR - 1);
    int n0 = c * CS;

    int I = min((int)floorf((float)n0 * KPOS), F_ - 2);
    int I2 = min(I + 2, F_ - 1);
    const float* Cb = coef + (size_t)b * F_ * 5;
    float cA[5], cB[5], cC[5];
    #pragma unroll
    for (int j = 0; j < 5; ++j) {
        cA[j] = Cb[I * 5 + j];
        cB[j] = Cb[(I + 1) * 5 + j];
        cC[j] = Cb[I2 * 5 + j];
    }
    float s0 = states[((size_t)b * CPR + c) * 2 + 0];   // y[n0-1]
    float s1 = states[((size_t)b * CPR + c) * 2 + 1];   // y[n0-2]

    const float* xp = x + (size_t)b * N_ + n0;
    float*       op = out + (size_t)b * N_ + n0;
    #pragma unroll 8
    for (int k = 0; k < CS; ++k) {
        float xn = xp[k];
        float pos = (float)(n0 + k) * KPOS;
        int i0 = min((int)floorf(pos), F_ - 2);
        float frac = pos - (float)i0;
        float om = 1.0f - frac;
        bool sel = i0 > I;
        float a1 = om * (sel ? cB[0] : cA[0]) + frac * (sel ? cC[0] : cB[0]);
        float a2 = om * (sel ? cB[1] : cA[1]) + frac * (sel ? cC[1] : cB[1]);
        float b0 = om * (sel ? cB[2] : cA[2]) + frac * (sel ? cC[2] : cB[2]);
        float b1 = om * (sel ? cB[3] : cA[3]) + frac * (sel ? cC[3] : cB[3]);
        float b2 = om * (sel ? cB[4] : cA[4]) + frac * (sel ? cC[4] : cB[4]);
        float y = xn - a1 * s0 - a2 * s1;
        op[k] = b0 * y + b1 * s0 + b2 * s1;
        s1 = s0; s0 = y;
    }
}

extern "C" void kernel_launch(void* const* d_in, const int* in_sizes, int n_in,
                              void* d_out, int out_size, void* d_ws, size_t ws_size,
                              hipStream_t stream) {
    const float* x      = (const float*)d_in[0];   // (B, N) f32
    const float* logits = (const float*)d_in[1];   // (B, F, 5) f32
    float* out = (float*)d_out;                    // (B, N) f32
    float* ws  = (float*)d_ws;

    float* coef   = ws + OFF_COEF;
    float* trans  = ws + OFF_TRANS;
    float* states = ws + OFF_STATES;

    coeff_kernel<<<(B_ * F_ + 255) / 256, 256, 0, stream>>>(logits, coef);
    phase1_kernel<<<(B_ * CPR + 255) / 256, 256, 0, stream>>>(x, coef, trans);
    scan_kernel<<<B_, CPR, 0, stream>>>(trans, states);
    phase3_kernel<<<(B_ * CPR + 255) / 256, 256, 0, stream>>>(x, coef, states, out);
}

// Round 2
// 108.950 us; speedup vs baseline: 1.1529x; 1.1529x over previous
//
#include <hip/hip_runtime.h>
#include <hip/hip_bf16.h>

#define B_   128
#define N_   65536
#define F_   512
#define CS   64
#define CPR  (N_ / CS)          // 1024 chunks per row
#define TPB  128                // chunks (threads) per block
#define BLK_SAMP (TPB * CS)     // 8192 samples per block
#define NBLK (B_ * CPR / TPB)   // 1024 blocks
#define KPOS ((float)(511.0 / 65535.0))
#define STRIDE 68               // padded LDS row stride (floats): 16B-aligned cols, conflict-free

// ws layout (floats), all SoA:
//   coef   [B_*F_*5]                     : 327680
//   trans  [6][B_*CPR]                   : 786432
//   states [2][B_*CPR]                   : 262144
#define OFF_COEF   0
#define OFF_TRANS  (B_ * F_ * 5)
#define OFF_STATES (OFF_TRANS + 6 * B_ * CPR)
#define NT (B_ * CPR)

__global__ void coeff_kernel(const float* __restrict__ logits, float* __restrict__ coef) {
    int t = blockIdx.x * blockDim.x + threadIdx.x;
    if (t >= B_ * F_) return;
    const float* L = logits + (size_t)t * 5;
    float l0 = L[0], l1 = L[1], l2 = L[2], l3 = L[3], l4 = L[4];
    float a1 = 2.0f * tanhf(l0);
    float ab = fabsf(a1);
    float a2 = 0.5f * ((2.0f - ab) * tanhf(l1) + ab);
    float* C = coef + (size_t)t * 5;
    C[0] = a1; C[1] = a2; C[2] = l2; C[3] = l3; C[4] = l4;
}

// Phase 1: per-chunk affine-transform composition. x staged through LDS so
// global reads are fully coalesced float4; trans stored SoA (coalesced).
__global__ __launch_bounds__(TPB) void phase1_kernel(const float* __restrict__ x,
                                                     const float* __restrict__ coef,
                                                     float* __restrict__ trans) {
    __shared__ __align__(16) float buf[TPB][STRIDE];
    int tid = threadIdx.x;
    int gchunk0 = blockIdx.x * TPB;                 // block's first global chunk

    const float4* xg = (const float4*)x + (size_t)gchunk0 * (CS / 4);
    #pragma unroll
    for (int it = 0; it < BLK_SAMP / 4 / TPB; ++it) {   // 16 coalesced float4 loads
        int i4 = it * TPB + tid;
        float4 v = xg[i4];
        int c = i4 >> 4;
        int k = (i4 & 15) * 4;
        *(float4*)&buf[c][k] = v;
    }
    __syncthreads();

    int t = gchunk0 + tid;          // global chunk id
    int b = t >> 10;
    int c = t & (CPR - 1);
    int n0 = c * CS;

    int I  = min((int)floorf((float)n0 * KPOS), F_ - 2);
    int I2 = min(I + 2, F_ - 1);
    const float* Cb = coef + (size_t)b * F_ * 5;
    float a1A = Cb[I * 5 + 0],       a2A = Cb[I * 5 + 1];
    float a1B = Cb[(I + 1) * 5 + 0], a2B = Cb[(I + 1) * 5 + 1];
    float a1C = Cb[I2 * 5 + 0],      a2C = Cb[I2 * 5 + 1];

    float A00 = 1.f, A01 = 0.f, A10 = 0.f, A11 = 1.f, v0 = 0.f, v1 = 0.f;
    #pragma unroll 4
    for (int j = 0; j < CS / 4; ++j) {
        float4 xv = *(const float4*)&buf[tid][j * 4];
        #pragma unroll
        for (int u = 0; u < 4; ++u) {
            int k = j * 4 + u;
            float xn = (&xv.x)[u];
            float pos = (float)(n0 + k) * KPOS;
            int i0 = min((int)floorf(pos), F_ - 2);
            float frac = pos - (float)i0;
            float om = 1.0f - frac;
            bool sel = i0 > I;
            float a1 = om * (sel ? a1B : a1A) + frac * (sel ? a1C : a1B);
            float a2 = om * (sel ? a2B : a2A) + frac * (sel ? a2C : a2B);
            float nA00 = -a1 * A00 - a2 * A10;
            float nA01 = -a1 * A01 - a2 * A11;
            float nv0  = xn - a1 * v0 - a2 * v1;
            A10 = A00; A11 = A01; v1 = v0;
            A00 = nA00; A01 = nA01; v0 = nv0;
        }
    }
    trans[0 * NT + t] = A00;
    trans[1 * NT + t] = A01;
    trans[2 * NT + t] = A10;
    trans[3 * NT + t] = A11;
    trans[4 * NT + t] = v0;
    trans[5 * NT + t] = v1;
}

// One block per row: Hillis-Steele scan over 1024 chunk transforms (SoA LDS).
__global__ __launch_bounds__(1024) void scan_kernel(const float* __restrict__ trans,
                                                    float* __restrict__ states) {
    __shared__ float s0[CPR], s1[CPR], s2[CPR], s3[CPR], s4[CPR], s5[CPR];
    int b = blockIdx.x;
    int c = threadIdx.x;
    size_t base = (size_t)b * CPR + c;
    float A00 = trans[0 * NT + base], A01 = trans[1 * NT + base];
    float A10 = trans[2 * NT + base], A11 = trans[3 * NT + base];
    float v0  = trans[4 * NT + base], v1  = trans[5 * NT + base];
    for (int d = 1; d < CPR; d <<= 1) {
        s0[c] = A00; s1[c] = A01; s2[c] = A10; s3[c] = A11; s4[c] = v0; s5[c] = v1;
        __syncthreads();
        if (c >= d) {
            float f00 = s0[c - d], f01 = s1[c - d];
            float f10 = s2[c - d], f11 = s3[c - d];
            float fv0 = s4[c - d], fv1 = s5[c - d];
            float n00 = A00 * f00 + A01 * f10;
            float n01 = A00 * f01 + A01 * f11;
            float n10 = A10 * f00 + A11 * f10;
            float n11 = A10 * f01 + A11 * f11;
            float nv0 = A00 * fv0 + A01 * fv1 + v0;
            float nv1 = A10 * fv0 + A11 * fv1 + v1;
            A00 = n00; A01 = n01; A10 = n10; A11 = n11; v0 = nv0; v1 = nv1;
        }
        __syncthreads();
    }
    float* st0 = states;
    float* st1 = states + NT;
    size_t rb = (size_t)b * CPR;
    if (c == 0) { st0[rb] = 0.f; st1[rb] = 0.f; }
    if (c < CPR - 1) { st0[rb + c + 1] = v0; st1[rb + c + 1] = v1; }
}

// Phase 3: exact recurrence from scanned start state + fused FIR.
// x staged in via LDS (coalesced float4), y staged out via LDS (coalesced float4).
__global__ __launch_bounds__(TPB) void phase3_kernel(const float* __restrict__ x,
                                                     const float* __restrict__ coef,
                                                     const float* __restrict__ states,
                                                     float* __restrict__ out) {
    __shared__ __align__(16) float buf[TPB][STRIDE];
    int tid = threadIdx.x;
    int gchunk0 = blockIdx.x * TPB;

    const float4* xg = (const float4*)x + (size_t)gchunk0 * (CS / 4);
    #pragma unroll
    for (int it = 0; it < BLK_SAMP / 4 / TPB; ++it) {
        int i4 = it * TPB + tid;
        float4 v = xg[i4];
        int c = i4 >> 4;
        int k = (i4 & 15) * 4;
        *(float4*)&buf[c][k] = v;
    }
    __syncthreads();

    int t = gchunk0 + tid;
    int b = t >> 10;
    int c = t & (CPR - 1);
    int n0 = c * CS;

    int I  = min((int)floorf((float)n0 * KPOS), F_ - 2);
    int I2 = min(I + 2, F_ - 1);
    const float* Cb = coef + (size_t)b * F_ * 5;
    float cA[5], cB[5], cC[5];
    #pragma unroll
    for (int j = 0; j < 5; ++j) {
        cA[j] = Cb[I * 5 + j];
        cB[j] = Cb[(I + 1) * 5 + j];
        cC[j] = Cb[I2 * 5 + j];
    }
    float s0v = states[t];        // y[n0-1]
    float s1v = states[NT + t];   // y[n0-2]

    #pragma unroll 4
    for (int j = 0; j < CS / 4; ++j) {
        float4 xv = *(const float4*)&buf[tid][j * 4];
        float4 yv;
        #pragma unroll
        for (int u = 0; u < 4; ++u) {
            int k = j * 4 + u;
            float xn = (&xv.x)[u];
            float pos = (float)(n0 + k) * KPOS;
            int i0 = min((int)floorf(pos), F_ - 2);
            float frac = pos - (float)i0;
            float om = 1.0f - frac;
            bool sel = i0 > I;
            float a1 = om * (sel ? cB[0] : cA[0]) + frac * (sel ? cC[0] : cB[0]);
            float a2 = om * (sel ? cB[1] : cA[1]) + frac * (sel ? cC[1] : cB[1]);
            float b0 = om * (sel ? cB[2] : cA[2]) + frac * (sel ? cC[2] : cB[2]);
            float b1 = om * (sel ? cB[3] : cA[3]) + frac * (sel ? cC[3] : cB[3]);
            float b2 = om * (sel ? cB[4] : cA[4]) + frac * (sel ? cC[4] : cB[4]);
            float y = xn - a1 * s0v - a2 * s1v;
            (&yv.x)[u] = b0 * y + b1 * s0v + b2 * s1v;
            s1v = s0v; s0v = y;
        }
        *(float4*)&buf[tid][j * 4] = yv;   // own row only — no cross-thread hazard
    }
    __syncthreads();

    float4* og = (float4*)out + (size_t)gchunk0 * (CS / 4);
    #pragma unroll
    for (int it = 0; it < BLK_SAMP / 4 / TPB; ++it) {
        int i4 = it * TPB + tid;
        int cc = i4 >> 4;
        int k = (i4 & 15) * 4;
        og[i4] = *(float4*)&buf[cc][k];
    }
}

extern "C" void kernel_launch(void* const* d_in, const int* in_sizes, int n_in,
                              void* d_out, int out_size, void* d_ws, size_t ws_size,
                              hipStream_t stream) {
    const float* x      = (const float*)d_in[0];   // (B, N) f32
    const float* logits = (const float*)d_in[1];   // (B, F, 5) f32
    float* out = (float*)d_out;                    // (B, N) f32
    float* ws  = (float*)d_ws;

    float* coef   = ws + OFF_COEF;
    float* trans  = ws + OFF_TRANS;
    float* states = ws + OFF_STATES;

    coeff_kernel<<<(B_ * F_ + 255) / 256, 256, 0, stream>>>(logits, coef);
    phase1_kernel<<<NBLK, TPB, 0, stream>>>(x, coef, trans);
    scan_kernel<<<B_, CPR, 0, stream>>>(trans, states);
    phase3_kernel<<<NBLK, TPB, 0, stream>>>(x, coef, states, out);
}